// Round 7
// baseline (785.887 us; speedup 1.0000x reference)
//
#include <hip/hip_runtime.h>
#include <hip/hip_fp8.h>
#include <math.h>

typedef _Float16 half_t;
typedef __attribute__((ext_vector_type(8))) _Float16 half8;
typedef __attribute__((ext_vector_type(16))) float floatx16;

#define LO_SCALE 512.0f
#define INV_LO   0.001953125f  // 1/512

__device__ __forceinline__ float gelu_exact(float v) {
    return 0.5f * v * (1.0f + erff(v * 0.7071067811865476f));
}

__device__ __forceinline__ floatx16 zero16() {
    floatx16 z;
#pragma unroll
    for (int i = 0; i < 16; ++i) z[i] = 0.f;
    return z;
}

__device__ __forceinline__ unsigned char to_fp8(float v) {
    __hip_fp8_e4m3 f(v);
    return f.__x;
}

#define MFMA16(a, b, c) __builtin_amdgcn_mfma_f32_32x32x16_f16((a), (b), (c), 0, 0, 0)
#define MFMA8(a, b, c)  __builtin_amdgcn_mfma_f32_32x32x16_fp8_fp8((a), (b), (c), 0, 0, 0)

// ---------------- prep ----------------
// W [h][k][n] fp32 -> Wsw f16 (hi) and Wsw8 fp8 (full value), B-fragment-swizzled:
//   element (k,n): ks=k>>4, j=n>>5, l=32*((k>>3)&1)+(n&31), jj=k&7  (validated r3-r5)
// Za tables [32 n][256 k]: row 2h = W[h]·A[h][0:256], 2h+1 = W[h]·A[h][256:512]
//   Zah f16 hi, Zal f16 residual*512, Za8 fp8 full value  (validated r4)
__global__ __launch_bounds__(256) void prep(const float* __restrict__ W0,
                                            const float* __restrict__ A0,
                                            const float* __restrict__ W1,
                                            const float* __restrict__ A1,
                                            half_t* __restrict__ Wsw0, half_t* __restrict__ Wsw1,
                                            unsigned char* __restrict__ Wsw8_0,
                                            unsigned char* __restrict__ Wsw8_1,
                                            half_t* __restrict__ Zah0, half_t* __restrict__ Zal0,
                                            unsigned char* __restrict__ Za8_0,
                                            half_t* __restrict__ Zah1, half_t* __restrict__ Zal1,
                                            unsigned char* __restrict__ Za8_1) {
    __shared__ float tile[32][257];
    const int t  = threadIdx.x;
    const int kb = blockIdx.x & 7;
    const int h  = (blockIdx.x >> 3) & 3;
    const int tz = blockIdx.x >> 5;
    const float* W = tz ? W1 : W0;
    const float* A = tz ? A1 : A0;
    half_t* Wsw = tz ? Wsw1 : Wsw0;
    unsigned char* W8 = tz ? Wsw8_1 : Wsw8_0;
    half_t* Zh  = tz ? Zah1 : Zah0;
    half_t* Zl  = tz ? Zal1 : Zal0;
    unsigned char* Z8 = tz ? Za8_1 : Za8_0;

    for (int i = 0; i < 32; ++i)
        tile[i][t] = W[(size_t)(h * 256 + kb * 32 + i) * 256 + t];
    __syncthreads();

    const int j = t >> 5, lmn = t & 31;
#pragma unroll
    for (int i0 = 0; i0 < 32; i0 += 8) {
        const int ks = 2 * kb + (i0 >> 4);
        const int q  = (i0 >> 3) & 1;
        half_t hb[8];
        unsigned long long pk = 0ull;
#pragma unroll
        for (int ii = 0; ii < 8; ++ii) {
            float v = tile[i0 + ii][t];
            hb[ii] = (half_t)v;
            pk |= ((unsigned long long)to_fp8(v)) << (8 * ii);
        }
        size_t off = ((size_t)(h * 16 + ks) * 8 + j) * 512 + (size_t)(32 * q + lmn) * 8;
        *(half8*)&Wsw[off] = *(half8*)hb;
        *(unsigned long long*)&W8[off] = pk;
    }

    if (kb == 0) {
        const float4* Wr = (const float4*)&W[(size_t)(h * 256 + t) * 256];
        const float4* Al = (const float4*)&A[h * 512];
        const float4* Ah = (const float4*)&A[h * 512 + 256];
        float wl = 0.f, wh = 0.f;
        for (int d = 0; d < 64; ++d) {
            float4 wv = Wr[d], a0 = Al[d], a1 = Ah[d];
            wl += wv.x * a0.x + wv.y * a0.y + wv.z * a0.z + wv.w * a0.w;
            wh += wv.x * a1.x + wv.y * a1.y + wv.z * a1.z + wv.w * a1.w;
        }
        half_t hi = (half_t)wl;
        Zh[(2 * h) * 256 + t] = hi;
        Zl[(2 * h) * 256 + t] = (half_t)((wl - (float)hi) * LO_SCALE);
        Z8[(2 * h) * 256 + t] = to_fp8(wl);
        hi = (half_t)wh;
        Zh[(2 * h + 1) * 256 + t] = hi;
        Zl[(2 * h + 1) * 256 + t] = (half_t)((wh - (float)hi) * LO_SCALE);
        Z8[(2 * h + 1) * 256 + t] = to_fp8(wh);
        if (h == 0) {
            for (int c = 8; c < 32; ++c) {
                Zh[c * 256 + t] = (half_t)0.f;
                Zl[c * 256 + t] = (half_t)0.f;
                Z8[c * 256 + t] = 0;
            }
        }
    }
}

// ---------------- fused GAT layer (r5 structure + fp8 lo plane) ----------------
// ROWS = 16*GROUPS rows/block; wave w owns cols [64w, 64w+64) of each head.
// Per head: pass-hi (f16 x_hi · f16 W) then pass-lo (fp8 512*x_lo · fp8 W),
// both folded into tp (lo scaled by 1/512) before gelu. 64 live acc regs.
// LDS = 32K (xsh) + 16K (xsl8) + 4K = 52 KB -> 3 blocks/CU at launch_bounds(256,3).
template <int GROUPS>
__global__ __launch_bounds__(256, 3) void gat_layer(
    const float* __restrict__ x,
    const half_t* __restrict__ Wsw, const unsigned char* __restrict__ Wsw8,
    const half_t* __restrict__ Zah, const half_t* __restrict__ Zal,
    const unsigned char* __restrict__ Za8,
    float* __restrict__ out) {
    constexpr int ROWS = GROUPS * 16;
    constexpr int MT   = ROWS / 32;

    __shared__ half_t xsh[MT * 16 * 512];                          // A-frags f16 hi
    __shared__ __align__(16) unsigned char xsl8[MT * 16 * 512];    // A-frags fp8 lo*512
    __shared__ float zlo_s[4][ROWS];
    __shared__ float zhi_s[4][ROWS];
    __shared__ float ge_s[4][ROWS];
    __shared__ float att_s[4][ROWS];

    const int t  = threadIdx.x;
    const int w  = t >> 6;
    const int l  = t & 63;
    const int lm = t & 31;
    const int q  = (t >> 5) & 1;

    // ---- stage x -> LDS A-fragment layout ----
    {
        const float4* xg = (const float4*)(x + (size_t)blockIdx.x * ROWS * 256);
#pragma unroll
        for (int i = 0; i < ROWS / 8; ++i) {
            int e = t + 256 * i;
            int row = e >> 5, cc = e & 31;          // k chunk of 8: k0 = 8*cc
            float4 v0 = xg[row * 64 + 2 * cc];
            float4 v1 = xg[row * 64 + 2 * cc + 1];
            half_t hb[8];
            unsigned long long pk = 0ull;
#pragma unroll
            for (int ii = 0; ii < 8; ++ii) {
                float v = (ii < 4) ? (&v0.x)[ii] : (&v1.x)[ii - 4];
                half_t hv = (half_t)v;
                hb[ii] = hv;
                pk |= ((unsigned long long)to_fp8((v - (float)hv) * LO_SCALE)) << (8 * ii);
            }
            int m = row >> 5, r31 = row & 31, ks = cc >> 1, kq = cc & 1;
            int ci = (m * 16 + ks) * 64 + 32 * kq + r31;
            *(half8*)&xsh[ci * 8] = *(half8*)hb;
            *(unsigned long long*)&xsl8[ci * 8] = pk;
        }
    }
    __syncthreads();

    // ---- z-tile (wave 0 only): z = x @ (W·A), all 4 heads in cols 0..7 ----
    if (w == 0) {
        floatx16 zm[MT], zc[MT], z8a[MT];
#pragma unroll
        for (int mt = 0; mt < MT; ++mt) { zm[mt] = zero16(); zc[mt] = zero16(); z8a[mt] = zero16(); }
#pragma unroll 4
        for (int ks = 0; ks < 16; ++ks) {
            const int ko = lm * 256 + 16 * ks + 8 * q;
            half8 bh = *(const half8*)&Zah[ko];
            half8 bl = *(const half8*)&Zal[ko];
            long  b8 = *(const long*)&Za8[ko];
#pragma unroll
            for (int mt = 0; mt < MT; ++mt) {
                int ci = (mt * 16 + ks) * 64 + l;
                half8 a  = *(const half8*)&xsh[ci * 8];
                long  a8 = *(const long*)&xsl8[ci * 8];
                zm[mt]  = MFMA16(a, bh, zm[mt]);
                zc[mt]  = MFMA16(a, bl, zc[mt]);   // xh · (Wa_lo*512)
                z8a[mt] = MFMA8(a8, b8, z8a[mt]);  // (xl*512) · Wa
            }
        }
        if (lm < 8) {
            int h = lm >> 1;
            float* dst = (lm & 1) ? &zhi_s[h][0] : &zlo_s[h][0];
#pragma unroll
            for (int mt = 0; mt < MT; ++mt)
#pragma unroll
                for (int r = 0; r < 16; ++r) {
                    int row = 32 * mt + 4 * q + (r & 3) + 8 * (r >> 2);
                    dst[row] = zm[mt][r] + (zc[mt][r] + z8a[mt][r]) * INV_LO;
                }
        }
    }
    __syncthreads();

    // ---- attention weights ----
    {
        int h = t >> 6, r = t & 63;
        if (r < ROWS) {
            float z = zlo_s[h][r] + zhi_s[h][r & ~15];
            ge_s[h][r] = gelu_exact(gelu_exact(z));
        }
    }
    __syncthreads();
    {
        int h = t >> 6, r = t & 63;
        if (r < ROWS) {
            int g0 = r & ~15;
            float mx = -1e30f;
#pragma unroll
            for (int i = 0; i < 16; ++i) mx = fmaxf(mx, ge_s[h][g0 + i]);
            float s = 0.f;
#pragma unroll
            for (int i = 0; i < 16; ++i) s += expf(ge_s[h][g0 + i] - mx);
            att_s[h][r] = expf(ge_s[h][r] - mx) / s;
        }
    }
    __syncthreads();

    // ---- main GEMM: per head, sequential hi(f16)/lo(fp8) passes, one acc set ----
    float outp[2][GROUPS];
#pragma unroll
    for (int nt = 0; nt < 2; ++nt)
#pragma unroll
        for (int g = 0; g < GROUPS; ++g) outp[nt][g] = 0.f;

#pragma unroll 1
    for (int h = 0; h < 4; ++h) {
        float tp[2][GROUPS];
#pragma unroll
        for (int nt = 0; nt < 2; ++nt)
#pragma unroll
            for (int g = 0; g < GROUPS; ++g) tp[nt][g] = 0.f;

        // ---- pass 1: f16 hi ----
        {
            const half_t* Bp = Wsw + ((size_t)(h * 16) * 8 + 2 * w) * 512 + (size_t)l * 8;
            floatx16 acc[MT][2];
#pragma unroll
            for (int mt = 0; mt < MT; ++mt) { acc[mt][0] = zero16(); acc[mt][1] = zero16(); }
#pragma unroll
            for (int ks = 0; ks < 16; ++ks) {
                half8 b0 = *(const half8*)(Bp + (size_t)ks * 4096);
                half8 b1 = *(const half8*)(Bp + (size_t)ks * 4096 + 512);
#pragma unroll
                for (int mt = 0; mt < MT; ++mt) {
                    half8 a = *(const half8*)&xsh[((mt * 16 + ks) * 64 + l) * 8];
                    acc[mt][0] = MFMA16(a, b0, acc[mt][0]);
                    acc[mt][1] = MFMA16(a, b1, acc[mt][1]);
                }
            }
#pragma unroll
            for (int mt = 0; mt < MT; ++mt)
#pragma unroll
                for (int k = 0; k < 4; ++k) {
                    float4 a4 = *(const float4*)&att_s[h][32 * mt + 4 * q + 8 * k];
#pragma unroll
                    for (int jj = 0; jj < 4; ++jj) {
                        int r = 4 * k + jj;
                        int row = 32 * mt + 4 * q + 8 * k + jj;
                        int g = row >> 4;
                        float av = (&a4.x)[jj];
                        tp[0][g] = fmaf(acc[mt][0][r], av, tp[0][g]);
                        tp[1][g] = fmaf(acc[mt][1][r], av, tp[1][g]);
                    }
                }
        }

        // ---- pass 2: fp8 lo residual (512*x_lo · W), folded with 1/512 ----
        {
            const unsigned char* Bp = Wsw8 + ((size_t)(h * 16) * 8 + 2 * w) * 512 + (size_t)l * 8;
            floatx16 acc[MT][2];
#pragma unroll
            for (int mt = 0; mt < MT; ++mt) { acc[mt][0] = zero16(); acc[mt][1] = zero16(); }
#pragma unroll
            for (int ks = 0; ks < 16; ++ks) {
                long b0 = *(const long*)(Bp + (size_t)ks * 4096);
                long b1 = *(const long*)(Bp + (size_t)ks * 4096 + 512);
#pragma unroll
                for (int mt = 0; mt < MT; ++mt) {
                    long a = *(const long*)&xsl8[((mt * 16 + ks) * 64 + l) * 8];
                    acc[mt][0] = MFMA8(a, b0, acc[mt][0]);
                    acc[mt][1] = MFMA8(a, b1, acc[mt][1]);
                }
            }
#pragma unroll
            for (int mt = 0; mt < MT; ++mt)
#pragma unroll
                for (int k = 0; k < 4; ++k) {
                    float4 a4 = *(const float4*)&att_s[h][32 * mt + 4 * q + 8 * k];
#pragma unroll
                    for (int jj = 0; jj < 4; ++jj) {
                        int r = 4 * k + jj;
                        int row = 32 * mt + 4 * q + 8 * k + jj;
                        int g = row >> 4;
                        float av = (&a4.x)[jj] * INV_LO;
                        tp[0][g] = fmaf(acc[mt][0][r], av, tp[0][g]);
                        tp[1][g] = fmaf(acc[mt][1][r], av, tp[1][g]);
                    }
                }
        }

        // gelu + head accumulation (fold q-halves)
#pragma unroll
        for (int nt = 0; nt < 2; ++nt)
#pragma unroll
            for (int g = 0; g < GROUPS; ++g) {
                float s = tp[nt][g] + __shfl_xor(tp[nt][g], 32, 64);
                outp[nt][g] += gelu_exact(s);
            }
    }

    // ---- store: wave w owns cols 64w..64w+63 of every head -> direct global ----
    if (q == 0) {
#pragma unroll
        for (int g = 0; g < GROUPS; ++g) {
            size_t ro = ((size_t)blockIdx.x * GROUPS + g) * 256 + 64 * w;
            out[ro + lm]      = 0.25f * outp[0][g];
            out[ro + 32 + lm] = 0.25f * outp[1][g];
        }
    }
}

extern "C" void kernel_launch(void* const* d_in, const int* in_sizes, int n_in,
                              void* d_out, int out_size, void* d_ws, size_t ws_size,
                              hipStream_t stream) {
    const float* x  = (const float*)d_in[0];
    const float* W0 = (const float*)d_in[1];
    const float* A0 = (const float*)d_in[2];
    const float* W1 = (const float*)d_in[3];
    const float* A1 = (const float*)d_in[4];

    char* ws = (char*)d_ws;
    float*         y1     = (float*)ws;                        // 8 MiB
    half_t*        Wsw0   = (half_t*)(ws + 8388608);           // 512 KiB
    half_t*        Wsw1   = (half_t*)(ws + 8912896);           // 512 KiB
    unsigned char* Wsw8_0 = (unsigned char*)(ws + 9437184);    // 256 KiB
    unsigned char* Wsw8_1 = (unsigned char*)(ws + 9699328);    // 256 KiB
    half_t*        Zah0   = (half_t*)(ws + 9961472);           // 16 KiB each
    half_t*        Zal0   = (half_t*)(ws + 9977856);
    half_t*        Zah1   = (half_t*)(ws + 9994240);
    half_t*        Zal1   = (half_t*)(ws + 10010624);
    unsigned char* Za8_0  = (unsigned char*)(ws + 10027008);   // 8 KiB each
    unsigned char* Za8_1  = (unsigned char*)(ws + 10035200);

    prep<<<64, 256, 0, stream>>>(W0, A0, W1, A1, Wsw0, Wsw1, Wsw8_0, Wsw8_1,
                                 Zah0, Zal0, Za8_0, Zah1, Zal1, Za8_1);
    gat_layer<4><<<2048, 256, 0, stream>>>(x, Wsw0, Wsw8_0, Zah0, Zal0, Za8_0, y1);
    gat_layer<2><<<256, 256, 0, stream>>>(y1, Wsw1, Wsw8_1, Zah1, Zal1, Za8_1,
                                          (float*)d_out);
}